// Round 3
// baseline (197.985 us; speedup 1.0000x reference)
//
#include <hip/hip_runtime.h>
#include <hip/hip_bf16.h>

#define N 8192
#define FIN 256
#define FOUT 128
#define ALPHA 0.2f

typedef unsigned short ushort_t;
typedef __attribute__((ext_vector_type(8))) short short8;
typedef __attribute__((ext_vector_type(4))) float f32x4;

__device__ __forceinline__ ushort_t f2bf(float x) {
  __hip_bfloat16 b = __float2bfloat16(x);  // RNE
  return *reinterpret_cast<ushort_t*>(&b);
}

// ---------------- Kernel 1: h = X@W (fp32), s1 = h@a1, s2 = h@a2, hT = bf16(h)^T ----
__global__ __launch_bounds__(256) void k_h(const float* __restrict__ inp,
                                           const float* __restrict__ Wm,
                                           const float* __restrict__ av,
                                           ushort_t* __restrict__ hT,
                                           float* __restrict__ s1,
                                           float* __restrict__ s2) {
  __shared__ float in_lds[16][FIN];    // 16 KB
  __shared__ float h_tile[16][FOUT];   // 8 KB
  const int t = threadIdx.x;
  const int r0 = blockIdx.x * 16;

  for (int idx = t; idx < 16 * FIN; idx += 256) {
    int ii = idx >> 8, kk = idx & 255;
    in_lds[ii][kk] = inp[(size_t)(r0 + ii) * FIN + kk];
  }
  __syncthreads();

  const int c2 = (t & 63) * 2;  // column pair
  const int rg = t >> 6;        // row group: rows rg*4 .. rg*4+3
  float acc[4][2] = {};
  for (int k = 0; k < FIN; k += 4) {
    float4 iv[4];
#pragma unroll
    for (int q = 0; q < 4; ++q)
      iv[q] = *reinterpret_cast<const float4*>(&in_lds[rg * 4 + q][k]);
#pragma unroll
    for (int kk = 0; kk < 4; ++kk) {
      float2 wp = *reinterpret_cast<const float2*>(&Wm[(size_t)(k + kk) * FOUT + c2]);
#pragma unroll
      for (int q = 0; q < 4; ++q) {
        float x = reinterpret_cast<const float*>(&iv[q])[kk];
        acc[q][0] = fmaf(x, wp.x, acc[q][0]);
        acc[q][1] = fmaf(x, wp.y, acc[q][1]);
      }
    }
  }
#pragma unroll
  for (int q = 0; q < 4; ++q) {
    h_tile[rg * 4 + q][c2] = acc[q][0];
    h_tile[rg * 4 + q][c2 + 1] = acc[q][1];
  }
  __syncthreads();

  // s1/s2: wave w reduces rows 4w..4w+3 over 128 cols
  const int wv_ = t >> 6, lane = t & 63;
#pragma unroll
  for (int rr = 0; rr < 4; ++rr) {
    int row = wv_ * 4 + rr;
    float h0 = h_tile[row][lane], h1 = h_tile[row][lane + 64];
    float p1 = h0 * av[lane] + h1 * av[lane + 64];
    float p2 = h0 * av[FOUT + lane] + h1 * av[FOUT + lane + 64];
#pragma unroll
    for (int m = 32; m; m >>= 1) {
      p1 += __shfl_xor(p1, m);
      p2 += __shfl_xor(p2, m);
    }
    if (lane == 0) { s1[r0 + row] = p1; s2[r0 + row] = p2; }
  }

  // hT[c][r] = bf16(h[r][c])
  for (int idx = t; idx < 16 * FOUT; idx += 256) {
    int c = idx >> 4, ii = idx & 15;
    hT[(size_t)c * N + r0 + ii] = f2bf(h_tile[ii][c]);
  }
}

// ---------------- Kernel 1b: global max of s2 -------------------------------------
__global__ __launch_bounds__(256) void k_smax(const float* __restrict__ s2,
                                              float* __restrict__ outm) {
  __shared__ float red[4];
  const int t = threadIdx.x;
  float m = -1e30f;
  for (int i = t; i < N; i += 256) m = fmaxf(m, s2[i]);
#pragma unroll
  for (int d = 32; d; d >>= 1) m = fmaxf(m, __shfl_xor(m, d));
  if ((t & 63) == 0) red[t >> 6] = m;
  __syncthreads();
  if (t == 0) outm[0] = fmaxf(fmaxf(red[0], red[1]), fmaxf(red[2], red[3]));
}

// ---------------- Kernel 2: masked softmax + P@h (MFMA), barrier-free main loop ---
// 512 blocks x 512 threads (8 waves). Block owns 16 rows x 128 cols of output.
// Wave w owns k-slice j%256 in [32w, 32w+32) and accumulates a k-partial of the
// full 16x128 tile. ANTI-CAMPING: each (block,wave) walks the 32 j-tiles in a
// rotated order (phase), so the GPU's instantaneous adj footprint covers all
// DRAM channels instead of one 1KB column window in lockstep.
__global__ __launch_bounds__(512, 4) void k_attn(const int* __restrict__ adj,
                                                 const ushort_t* __restrict__ hT,
                                                 const float* __restrict__ s1g,
                                                 const float* __restrict__ s2g,
                                                 const float* __restrict__ s2max,
                                                 float* __restrict__ out) {
  __shared__ float Hred[16][132];  // padded -> <=2-way conflict
  __shared__ float Dred[8][16];

  const int t = threadIdx.x;
  const int lane = t & 63;
  const int wid = t >> 6;
  const int i0 = blockIdx.x * 16;
  const int row = lane & 15;   // A-frag row == adj row; also B-frag col
  const int kb = lane >> 4;    // k-subblock 0..3

  const float s1v = s1g[i0 + row];
  const float mraw = s1v + s2max[0];
  const float mv = mraw > 0.f ? mraw : ALPHA * mraw;  // m~_i >= max_j e_ij
  const float L2E = 1.44269504f;
  const float mvl = mv * L2E;

  const int phase = (blockIdx.x + wid * 4) & 31;  // per-(block,wave) tile rotation

  const int jw = wid * 32 + kb * 8;  // lane's base j within each 256-tile
  const int* __restrict__ adjp = adj + (size_t)(i0 + row) * N + jw;
  const float* __restrict__ s2p = s2g + jw;
  const ushort_t* __restrict__ bp = hT + (size_t)row * N + jw;  // + ct*16*N + tp*256

  f32x4 acc[8];
#pragma unroll
  for (int ct = 0; ct < 8; ++ct) acc[ct] = (f32x4){0.f, 0.f, 0.f, 0.f};
  float dacc = 0.f;

  // Body: B-loads FIRST, then prefetch issue, then VALU weights, then MFMA.
  // The MFMA's vmcnt wait thus leaves the adj prefetch in flight.
#define COMPUTE(C0, C1, G0, G1, TP)                                         \
  {                                                                         \
    const ushort_t* bb = bp + (TP) * 256;                                   \
    short8 bf[8];                                                           \
    _Pragma("unroll") for (int ct = 0; ct < 8; ++ct)                        \
      bf[ct] = *reinterpret_cast<const short8*>(bb + (size_t)ct * 16 * N);  \
    const int* ai = reinterpret_cast<const int*>(&(C0));                    \
    const int* ai2 = reinterpret_cast<const int*>(&(C1));                   \
    const float* sf = reinterpret_cast<const float*>(&(G0));                \
    const float* sf2 = reinterpret_cast<const float*>(&(G1));               \
    short8 af;                                                              \
    _Pragma("unroll") for (int e = 0; e < 4; ++e) {                         \
      float pre = s1v + sf[e];                                              \
      float lr = fmaxf(pre, ALPHA * pre);                                   \
      float w = __builtin_amdgcn_exp2f(fmaf(lr, L2E, -mvl));                \
      w = (ai[e] > 0) ? w : 0.f;                                            \
      dacc += w;                                                            \
      af[e] = (short)f2bf(w);                                               \
    }                                                                       \
    _Pragma("unroll") for (int e = 0; e < 4; ++e) {                         \
      float pre = s1v + sf2[e];                                             \
      float lr = fmaxf(pre, ALPHA * pre);                                   \
      float w = __builtin_amdgcn_exp2f(fmaf(lr, L2E, -mvl));                \
      w = (ai2[e] > 0) ? w : 0.f;                                           \
      dacc += w;                                                            \
      af[4 + e] = (short)f2bf(w);                                           \
    }                                                                       \
    _Pragma("unroll") for (int ct = 0; ct < 8; ++ct)                        \
      acc[ct] = __builtin_amdgcn_mfma_f32_16x16x32_bf16(af, bf[ct], acc[ct], 0, 0, 0); \
  }

  // 2-deep prefetch, slots A/B (no runtime-indexed arrays, rule #20).
  {
    const int o0 = phase * 256;                 // tile for it=0
    const int o1 = ((phase + 1) & 31) * 256;    // tile for it=1
    // (loads below issued up-front)
    // slot A <- it=0, slot B <- it=1
  }
  int4 aA0 = *reinterpret_cast<const int4*>(adjp + phase * 256);
  int4 aA1 = *reinterpret_cast<const int4*>(adjp + phase * 256 + 4);
  float4 sA0 = *reinterpret_cast<const float4*>(s2p + phase * 256);
  float4 sA1 = *reinterpret_cast<const float4*>(s2p + phase * 256 + 4);
  int4 aB0 = *reinterpret_cast<const int4*>(adjp + ((phase + 1) & 31) * 256);
  int4 aB1 = *reinterpret_cast<const int4*>(adjp + ((phase + 1) & 31) * 256 + 4);
  float4 sB0 = *reinterpret_cast<const float4*>(s2p + ((phase + 1) & 31) * 256);
  float4 sB1 = *reinterpret_cast<const float4*>(s2p + ((phase + 1) & 31) * 256 + 4);

  for (int it = 0; it < 32; it += 2) {
    {
      const int tp = (it + phase) & 31;
      int4 c0 = aA0, c1 = aA1;
      float4 g0 = sA0, g1 = sA1;
      if (it + 2 < 32) {
        const int of = ((it + 2 + phase) & 31) * 256;
        aA0 = *reinterpret_cast<const int4*>(adjp + of);
        aA1 = *reinterpret_cast<const int4*>(adjp + of + 4);
        sA0 = *reinterpret_cast<const float4*>(s2p + of);
        sA1 = *reinterpret_cast<const float4*>(s2p + of + 4);
      }
      COMPUTE(c0, c1, g0, g1, tp)
    }
    {
      const int tp = (it + 1 + phase) & 31;
      int4 c0 = aB0, c1 = aB1;
      float4 g0 = sB0, g1 = sB1;
      if (it + 3 < 32) {
        const int of = ((it + 3 + phase) & 31) * 256;
        aB0 = *reinterpret_cast<const int4*>(adjp + of);
        aB1 = *reinterpret_cast<const int4*>(adjp + of + 4);
        sB0 = *reinterpret_cast<const float4*>(s2p + of);
        sB1 = *reinterpret_cast<const float4*>(s2p + of + 4);
      }
      COMPUTE(c0, c1, g0, g1, tp)
    }
  }
#undef COMPUTE

  // ---- denominator: lanes {r, r+16, r+32, r+48} share row r ----
  dacc += __shfl_xor(dacc, 16);
  dacc += __shfl_xor(dacc, 32);
  if (lane < 16) Dred[wid][lane] = dacc;

  // ---- cross-wave reduction of the k-partial 16x128 tiles (one-time) ----
  // C/D layout (m89-verified): col = ct*16 + (lane&15), row = (lane>>4)*4 + r
  for (int wv = 0; wv < 8; ++wv) {
    if (wid == wv) {
#pragma unroll
      for (int ct = 0; ct < 8; ++ct)
#pragma unroll
        for (int r = 0; r < 4; ++r) {
          int orow = kb * 4 + r;
          int ocol = ct * 16 + row;
          if (wv == 0)
            Hred[orow][ocol] = acc[ct][r];
          else
            Hred[orow][ocol] += acc[ct][r];
        }
    }
    __syncthreads();
  }

  // ---- epilogue: divide by denom, ELU, store ----
  for (int idx = t; idx < 16 * FOUT; idx += 512) {
    int orow = idx >> 7, ocol = idx & 127;
    float den = 0.f;
#pragma unroll
    for (int wv = 0; wv < 8; ++wv) den += Dred[wv][orow];
    float v = Hred[orow][ocol] / den;
    out[(size_t)(i0 + orow) * FOUT + ocol] = v > 0.f ? v : (__expf(v) - 1.f);
  }
}

extern "C" void kernel_launch(void* const* d_in, const int* in_sizes, int n_in,
                              void* d_out, int out_size, void* d_ws, size_t ws_size,
                              hipStream_t stream) {
  const float* inp = (const float*)d_in[0];   // [N][FIN] fp32
  const int* adj   = (const int*)d_in[1];     // [N][N] int32
  const float* Wm  = (const float*)d_in[2];   // [FIN][FOUT] fp32
  const float* av  = (const float*)d_in[3];   // [2*FOUT] fp32
  float* out = (float*)d_out;

  // workspace carve-up
  char* ws = (char*)d_ws;
  ushort_t* hT = (ushort_t*)ws;                              // 128*8192*2 = 2 MB
  float* s1    = (float*)(ws + (size_t)FOUT * N * 2);        // 32 KB
  float* s2    = s1 + N;                                     // 32 KB
  float* s2mx  = s2 + N;                                     // 4 B

  k_h<<<N / 16, 256, 0, stream>>>(inp, Wm, av, hT, s1, s2);
  k_smax<<<1, 256, 0, stream>>>(s2, s2mx);
  k_attn<<<N / 16, 512, 0, stream>>>(adj, hT, s1, s2, s2mx, out);
}

// Round 4
// 125.746 us; speedup vs baseline: 1.5745x; 1.5745x over previous
//
#include <hip/hip_runtime.h>
#include <hip/hip_bf16.h>

#define N 8192
#define FIN 256
#define FOUT 128
#define ALPHA 0.2f

typedef unsigned short ushort_t;
typedef __attribute__((ext_vector_type(8))) short short8;
typedef __attribute__((ext_vector_type(4))) float f32x4;

#define GLOAD16(gp, lp)                                        \
  __builtin_amdgcn_global_load_lds(                            \
      (const __attribute__((address_space(1))) void*)(gp),     \
      (__attribute__((address_space(3))) void*)(lp), 16, 0, 0)

__device__ __forceinline__ ushort_t f2bf(float x) {
  __hip_bfloat16 b = __float2bfloat16(x);  // RNE
  return *reinterpret_cast<ushort_t*>(&b);
}

// ---------------- Kernel 1: h = X@W (fp32), s1 = h@a1, s2 = h@a2, hT = bf16(h)^T ----
__global__ __launch_bounds__(256) void k_h(const float* __restrict__ inp,
                                           const float* __restrict__ Wm,
                                           const float* __restrict__ av,
                                           ushort_t* __restrict__ hT,
                                           float* __restrict__ s1,
                                           float* __restrict__ s2) {
  __shared__ float in_lds[16][FIN];
  __shared__ float h_tile[16][FOUT];
  const int t = threadIdx.x;
  const int r0 = blockIdx.x * 16;

  for (int idx = t; idx < 16 * FIN; idx += 256) {
    int ii = idx >> 8, kk = idx & 255;
    in_lds[ii][kk] = inp[(size_t)(r0 + ii) * FIN + kk];
  }
  __syncthreads();

  const int c2 = (t & 63) * 2;
  const int rg = t >> 6;
  float acc[4][2] = {};
  for (int k = 0; k < FIN; k += 4) {
    float4 iv[4];
#pragma unroll
    for (int q = 0; q < 4; ++q)
      iv[q] = *reinterpret_cast<const float4*>(&in_lds[rg * 4 + q][k]);
#pragma unroll
    for (int kk = 0; kk < 4; ++kk) {
      float2 wp = *reinterpret_cast<const float2*>(&Wm[(size_t)(k + kk) * FOUT + c2]);
#pragma unroll
      for (int q = 0; q < 4; ++q) {
        float x = reinterpret_cast<const float*>(&iv[q])[kk];
        acc[q][0] = fmaf(x, wp.x, acc[q][0]);
        acc[q][1] = fmaf(x, wp.y, acc[q][1]);
      }
    }
  }
#pragma unroll
  for (int q = 0; q < 4; ++q) {
    h_tile[rg * 4 + q][c2] = acc[q][0];
    h_tile[rg * 4 + q][c2 + 1] = acc[q][1];
  }
  __syncthreads();

  const int wv_ = t >> 6, lane = t & 63;
#pragma unroll
  for (int rr = 0; rr < 4; ++rr) {
    int row = wv_ * 4 + rr;
    float h0 = h_tile[row][lane], h1 = h_tile[row][lane + 64];
    float p1 = h0 * av[lane] + h1 * av[lane + 64];
    float p2 = h0 * av[FOUT + lane] + h1 * av[FOUT + lane + 64];
#pragma unroll
    for (int m = 32; m; m >>= 1) {
      p1 += __shfl_xor(p1, m);
      p2 += __shfl_xor(p2, m);
    }
    if (lane == 0) { s1[r0 + row] = p1; s2[r0 + row] = p2; }
  }

  for (int idx = t; idx < 16 * FOUT; idx += 256) {
    int c = idx >> 4, ii = idx & 15;
    hT[(size_t)c * N + r0 + ii] = f2bf(h_tile[ii][c]);
  }
}

// ---------------- Kernel 1b: global max of s2 -------------------------------------
__global__ __launch_bounds__(256) void k_smax(const float* __restrict__ s2,
                                              float* __restrict__ outm) {
  __shared__ float red[4];
  const int t = threadIdx.x;
  float m = -1e30f;
  for (int i = t; i < N; i += 256) m = fmaxf(m, s2[i]);
#pragma unroll
  for (int d = 32; d; d >>= 1) m = fmaxf(m, __shfl_xor(m, d));
  if ((t & 63) == 0) red[t >> 6] = m;
  __syncthreads();
  if (t == 0) outm[0] = fmaxf(fmaxf(red[0], red[1]), fmaxf(red[2], red[3]));
}

// ---------------- Kernel 2: fused masked-softmax + P@h, hT-reuse-blocked ----------
// Block = 64 rows x jc-chunk of j. Per 256-j tile, the hT slice [128 ct][256 j]
// (64 KB) is staged ONCE into LDS via global_load_lds with pre-swizzled source
// (XOR ((row&7)<<4) on the byte offset) and shared by all 8 waves — cutting hT
// beyond-L2 traffic ~4x vs private reads. adj is read once, in A-fragment layout.
// Wave (g = wid&3, hf = wid>>2): rows g*16..+16, j-half hf*128 of each tile.
// Per-chunk numerator/denominator partials go to slabs (deterministic combine).
__global__ __launch_bounds__(512, 4) void k_attn(const int* __restrict__ adj,
                                                 const ushort_t* __restrict__ hT,
                                                 const float* __restrict__ s1g,
                                                 const float* __restrict__ s2g,
                                                 const float* __restrict__ s2max,
                                                 float* __restrict__ slab,
                                                 float* __restrict__ denp,
                                                 int jc, int ntiles) {
  __shared__ __align__(16) ushort_t Bt[32768];  // 64 KB staged hT tile
  __shared__ float Dred[8][16];

  const int t = threadIdx.x;
  const int lane = t & 63;
  const int wid = t >> 6;
  const int rb = blockIdx.x & 127;
  const int chunk = blockIdx.x >> 7;
  const int i0 = rb * 64;
  const int jc0 = chunk * jc;

  const int g = wid & 3;        // row-group
  const int hf = wid >> 2;      // j-half of tile
  const int arow = lane & 15;   // A-frag row / B-frag col
  const int kb = lane >> 4;     // k-slot 0..3
  const int irow = i0 + g * 16 + arow;

  const float s1v = s1g[irow];
  const float mraw = s1v + s2max[0];
  const float mv = mraw > 0.f ? mraw : ALPHA * mraw;  // >= max_j e_ij (monotone)
  const float L2E = 1.44269504f;
  const float mvl = mv * L2E;

  const int* __restrict__ adjp = adj + (size_t)irow * N + jc0 + hf * 128 + kb * 8;
  const float* __restrict__ s2p = s2g + jc0 + hf * 128 + kb * 8;
  const char* __restrict__ hTb = (const char*)hT;

  f32x4 acc[8];
#pragma unroll
  for (int ct = 0; ct < 8; ++ct) acc[ct] = (f32x4){0.f, 0.f, 0.f, 0.f};
  float dacc = 0.f;

  for (int jt = 0; jt < ntiles; ++jt) {
    const int j0 = jt * 256;

    // ---- stage hT[0:128][jc0+j0 : +256] -> Bt, linear dest + swizzled source ----
#pragma unroll
    for (int s = 0; s < 8; ++s) {
      int L = s * 512 + t;          // 16B-granule index
      int row = L >> 5;             // ct row 0..127
      int boff = (L & 31) * 16;     // byte offset in 512B row
      const char* src = hTb + ((size_t)row * N + jc0 + j0) * 2 + (boff ^ ((row & 7) << 4));
      GLOAD16(src, (char*)Bt + L * 16);
    }

    // ---- adj loads for this tile (A-fragment layout), issued before the barrier ----
    int4 a0[4], a1[4];
#pragma unroll
    for (int kq = 0; kq < 4; ++kq) {
      a0[kq] = *reinterpret_cast<const int4*>(adjp + j0 + kq * 32);
      a1[kq] = *reinterpret_cast<const int4*>(adjp + j0 + kq * 32 + 4);
    }

    __syncthreads();  // drains vmcnt: Bt staged, adj in regs

#pragma unroll
    for (int kq = 0; kq < 4; ++kq) {
      // B-fragments from LDS (swizzled read)
      short8 bf[8];
      const int byte0 = hf * 256 + kq * 64 + kb * 16;
#pragma unroll
      for (int ct = 0; ct < 8; ++ct) {
        int row = ct * 16 + arow;
        int off = row * 512 + (byte0 ^ ((row & 7) << 4));
        bf[ct] = *reinterpret_cast<const short8*>((const char*)Bt + off);
      }
      // attention weights -> A-fragment
      float4 sv0 = *reinterpret_cast<const float4*>(s2p + j0 + kq * 32);
      float4 sv1 = *reinterpret_cast<const float4*>(s2p + j0 + kq * 32 + 4);
      const int* ai0 = reinterpret_cast<const int*>(&a0[kq]);
      const int* ai1 = reinterpret_cast<const int*>(&a1[kq]);
      const float* sf0 = reinterpret_cast<const float*>(&sv0);
      const float* sf1 = reinterpret_cast<const float*>(&sv1);
      short8 af;
#pragma unroll
      for (int e = 0; e < 4; ++e) {
        float pre = s1v + sf0[e];
        float lr = fmaxf(pre, ALPHA * pre);
        float w = __builtin_amdgcn_exp2f(fmaf(lr, L2E, -mvl));
        w = (ai0[e] > 0) ? w : 0.f;
        dacc += w;
        af[e] = (short)f2bf(w);
      }
#pragma unroll
      for (int e = 0; e < 4; ++e) {
        float pre = s1v + sf1[e];
        float lr = fmaxf(pre, ALPHA * pre);
        float w = __builtin_amdgcn_exp2f(fmaf(lr, L2E, -mvl));
        w = (ai1[e] > 0) ? w : 0.f;
        dacc += w;
        af[4 + e] = (short)f2bf(w);
      }
#pragma unroll
      for (int ct = 0; ct < 8; ++ct)
        acc[ct] = __builtin_amdgcn_mfma_f32_16x16x32_bf16(af, bf[ct], acc[ct], 0, 0, 0);
    }

    __syncthreads();  // all waves done reading Bt before next stage
  }

  // ---- denominator partials: lanes {r, r+16, r+32, r+48} share row r ----
  dacc += __shfl_xor(dacc, 16);
  dacc += __shfl_xor(dacc, 32);
  if (lane < 16) Dred[wid][lane] = dacc;

  // ---- combine the two hf-halves' k-partials in LDS (reuse Bt) ----
  float (*Hred)[132] = (float(*)[132])(void*)Bt;  // 64 x 132 x 4B = 33.8 KB
  // C/D layout (m89-verified): col = ct*16 + arow, row-in-group = kb*4 + r
  if (hf == 0) {
#pragma unroll
    for (int ct = 0; ct < 8; ++ct)
#pragma unroll
      for (int r = 0; r < 4; ++r)
        Hred[g * 16 + kb * 4 + r][ct * 16 + arow] = acc[ct][r];
  }
  __syncthreads();
  if (hf == 1) {
#pragma unroll
    for (int ct = 0; ct < 8; ++ct)
#pragma unroll
      for (int r = 0; r < 4; ++r)
        Hred[g * 16 + kb * 4 + r][ct * 16 + arow] += acc[ct][r];
  }
  __syncthreads();

  if (t < 64)
    denp[(size_t)chunk * N + i0 + t] = Dred[t >> 4][t & 15] + Dred[(t >> 4) + 4][t & 15];

  for (int idx = t; idx < 64 * 128; idx += 512) {
    int r = idx >> 7, c = idx & 127;
    slab[((size_t)chunk * N + i0 + r) * 128 + c] = Hred[r][c];
  }
}

// ---------------- Kernel 3: combine chunks, divide, ELU ---------------------------
__global__ __launch_bounds__(256) void k_fin(const float* __restrict__ slab,
                                             const float* __restrict__ denp,
                                             float* __restrict__ out, int nchunks) {
  const int idx = blockIdx.x * 256 + threadIdx.x;  // < N*FOUT
  const int i = idx >> 7;
  float den = 0.f, v = 0.f;
  for (int k = 0; k < nchunks; ++k) {
    den += denp[(size_t)k * N + i];
    v += slab[(size_t)k * N * FOUT + idx];
  }
  v /= den;
  out[idx] = v > 0.f ? v : (__expf(v) - 1.f);
}

extern "C" void kernel_launch(void* const* d_in, const int* in_sizes, int n_in,
                              void* d_out, int out_size, void* d_ws, size_t ws_size,
                              hipStream_t stream) {
  const float* inp = (const float*)d_in[0];   // [N][FIN] fp32
  const int* adj   = (const int*)d_in[1];     // [N][N] int32
  const float* Wm  = (const float*)d_in[2];   // [FIN][FOUT] fp32
  const float* av  = (const float*)d_in[3];   // [2*FOUT] fp32
  float* out = (float*)d_out;

  // workspace carve-up
  char* ws = (char*)d_ws;
  ushort_t* hT = (ushort_t*)ws;                               // 2 MB
  float* s1    = (float*)(ws + (size_t)FOUT * N * 2);         // 32 KB
  float* s2    = s1 + N;                                      // 32 KB
  float* s2mx  = s2 + N;                                      // 16 B (padded)
  float* slab  = s2mx + 4;

  const size_t base = (size_t)FOUT * N * 2 + (size_t)N * 4 * 2 + 16;
  int nchunks = 4;
  while (nchunks > 1) {
    size_t need = base + (size_t)nchunks * N * FOUT * 4 + (size_t)nchunks * N * 4;
    if (need <= ws_size) break;
    nchunks >>= 1;
  }
  float* denp = slab + (size_t)nchunks * N * FOUT;
  const int jc = N / nchunks;
  const int ntiles = jc / 256;

  k_h<<<N / 16, 256, 0, stream>>>(inp, Wm, av, hT, s1, s2);
  k_smax<<<1, 256, 0, stream>>>(s2, s2mx);
  k_attn<<<128 * nchunks, 512, 0, stream>>>(adj, hT, s1, s2, s2mx, slab, denp, jc, ntiles);
  k_fin<<<(N * FOUT) / 256, 256, 0, stream>>>(slab, denp, out, nchunks);
}

// Round 5
// 121.547 us; speedup vs baseline: 1.6289x; 1.0346x over previous
//
#include <hip/hip_runtime.h>
#include <hip/hip_bf16.h>

#define N 8192
#define FIN 256
#define FOUT 128
#define ALPHA 0.2f

typedef unsigned short ushort_t;
typedef __attribute__((ext_vector_type(8))) short short8;
typedef __attribute__((ext_vector_type(4))) float f32x4;

#define GLOAD16(gp, lp)                                        \
  __builtin_amdgcn_global_load_lds(                            \
      (const __attribute__((address_space(1))) void*)(gp),     \
      (__attribute__((address_space(3))) void*)(lp), 16, 0, 0)

__device__ __forceinline__ ushort_t f2bf(float x) {
  __hip_bfloat16 b = __float2bfloat16(x);  // RNE
  return *reinterpret_cast<ushort_t*>(&b);
}

// ---------------- Kernel 0: pack adj>0 into a bitmask (8 MB) ----------------------
// Pure streaming read of adj (32 B contiguous per lane) — also the diagnostic for
// "how fast can adj be read at all". mask byte b holds bits for j in [8b, 8b+8),
// i.e. uint32 word w bit k = adj[.][32w+k] (little-endian bytes match).
__global__ __launch_bounds__(256) void k_pack(const int* __restrict__ adj,
                                              unsigned char* __restrict__ mask) {
  const size_t tid = (size_t)blockIdx.x * 256 + threadIdx.x;
  const size_t nthr = (size_t)gridDim.x * 256;
  const size_t total = (size_t)N * N / 8;  // output bytes
  for (size_t b = tid; b < total; b += nthr) {
    const int4* p = reinterpret_cast<const int4*>(adj + b * 8);
    int4 v0 = p[0], v1 = p[1];
    unsigned m = 0;
    m |= (v0.x > 0) ? 1u : 0u;
    m |= (v0.y > 0) ? 2u : 0u;
    m |= (v0.z > 0) ? 4u : 0u;
    m |= (v0.w > 0) ? 8u : 0u;
    m |= (v1.x > 0) ? 16u : 0u;
    m |= (v1.y > 0) ? 32u : 0u;
    m |= (v1.z > 0) ? 64u : 0u;
    m |= (v1.w > 0) ? 128u : 0u;
    mask[b] = (unsigned char)m;
  }
}

// ---------------- Kernel 1: h = X@W (fp32), s1 = h@a1, s2 = h@a2, hT = bf16(h)^T ----
__global__ __launch_bounds__(256) void k_h(const float* __restrict__ inp,
                                           const float* __restrict__ Wm,
                                           const float* __restrict__ av,
                                           ushort_t* __restrict__ hT,
                                           float* __restrict__ s1,
                                           float* __restrict__ s2) {
  __shared__ float in_lds[16][FIN];
  __shared__ float h_tile[16][FOUT];
  const int t = threadIdx.x;
  const int r0 = blockIdx.x * 16;

  for (int idx = t; idx < 16 * FIN; idx += 256) {
    int ii = idx >> 8, kk = idx & 255;
    in_lds[ii][kk] = inp[(size_t)(r0 + ii) * FIN + kk];
  }
  __syncthreads();

  const int c2 = (t & 63) * 2;
  const int rg = t >> 6;
  float acc[4][2] = {};
  for (int k = 0; k < FIN; k += 4) {
    float4 iv[4];
#pragma unroll
    for (int q = 0; q < 4; ++q)
      iv[q] = *reinterpret_cast<const float4*>(&in_lds[rg * 4 + q][k]);
#pragma unroll
    for (int kk = 0; kk < 4; ++kk) {
      float2 wp = *reinterpret_cast<const float2*>(&Wm[(size_t)(k + kk) * FOUT + c2]);
#pragma unroll
      for (int q = 0; q < 4; ++q) {
        float x = reinterpret_cast<const float*>(&iv[q])[kk];
        acc[q][0] = fmaf(x, wp.x, acc[q][0]);
        acc[q][1] = fmaf(x, wp.y, acc[q][1]);
      }
    }
  }
#pragma unroll
  for (int q = 0; q < 4; ++q) {
    h_tile[rg * 4 + q][c2] = acc[q][0];
    h_tile[rg * 4 + q][c2 + 1] = acc[q][1];
  }
  __syncthreads();

  const int wv_ = t >> 6, lane = t & 63;
#pragma unroll
  for (int rr = 0; rr < 4; ++rr) {
    int row = wv_ * 4 + rr;
    float h0 = h_tile[row][lane], h1 = h_tile[row][lane + 64];
    float p1 = h0 * av[lane] + h1 * av[lane + 64];
    float p2 = h0 * av[FOUT + lane] + h1 * av[FOUT + lane + 64];
#pragma unroll
    for (int m = 32; m; m >>= 1) {
      p1 += __shfl_xor(p1, m);
      p2 += __shfl_xor(p2, m);
    }
    if (lane == 0) { s1[r0 + row] = p1; s2[r0 + row] = p2; }
  }

  for (int idx = t; idx < 16 * FOUT; idx += 256) {
    int c = idx >> 4, ii = idx & 15;
    hT[(size_t)c * N + r0 + ii] = f2bf(h_tile[ii][c]);
  }
}

// ---------------- Kernel 1b: global max of s2 -------------------------------------
__global__ __launch_bounds__(256) void k_smax(const float* __restrict__ s2,
                                              float* __restrict__ outm) {
  __shared__ float red[4];
  const int t = threadIdx.x;
  float m = -1e30f;
  for (int i = t; i < N; i += 256) m = fmaxf(m, s2[i]);
#pragma unroll
  for (int d = 32; d; d >>= 1) m = fmaxf(m, __shfl_xor(m, d));
  if ((t & 63) == 0) red[t >> 6] = m;
  __syncthreads();
  if (t == 0) outm[0] = fmaxf(fmaxf(red[0], red[1]), fmaxf(red[2], red[3]));
}

// ---------------- Kernel 2: fused masked-softmax + P@h, bitmask edition -----------
// Identical structure to round 4 (hT staged once per tile into swizzled LDS, shared
// by 8 waves) but adj is consumed as the 8 MB L2-resident bitmask: one int4 (4
// words = 4 kq) per lane per 256-j tile instead of 128 B of int32 adj. Main loop
// touches no HBM stream -> measures pure structure cost.
__global__ __launch_bounds__(512, 4) void k_attn(const unsigned int* __restrict__ mask,
                                                 const ushort_t* __restrict__ hT,
                                                 const float* __restrict__ s1g,
                                                 const float* __restrict__ s2g,
                                                 const float* __restrict__ s2max,
                                                 float* __restrict__ slab,
                                                 float* __restrict__ denp,
                                                 int jc, int ntiles) {
  __shared__ __align__(16) ushort_t Bt[32768];  // 64 KB staged hT tile
  __shared__ float Dred[8][16];

  const int t = threadIdx.x;
  const int lane = t & 63;
  const int wid = t >> 6;
  const int rb = blockIdx.x & 127;
  const int chunk = blockIdx.x >> 7;
  const int i0 = rb * 64;
  const int jc0 = chunk * jc;

  const int g = wid & 3;        // row-group
  const int hf = wid >> 2;      // j-half of tile
  const int arow = lane & 15;   // A-frag row / B-frag col
  const int kb = lane >> 4;     // k-slot 0..3
  const int irow = i0 + g * 16 + arow;

  const float s1v = s1g[irow];
  const float mraw = s1v + s2max[0];
  const float mv = mraw > 0.f ? mraw : ALPHA * mraw;  // >= max_j e_ij (monotone)
  const float L2E = 1.44269504f;
  const float mvl = mv * L2E;

  // mask words for (irow, jc0 + hf*128 + j): word index irow*(N/32) + (jc0+hf*128+j0)/32 + kq
  const unsigned int* __restrict__ maskp =
      mask + (size_t)irow * (N / 32) + ((jc0 + hf * 128) >> 5);
  const float* __restrict__ s2p = s2g + jc0 + hf * 128 + kb * 8;
  const char* __restrict__ hTb = (const char*)hT;

  f32x4 acc[8];
#pragma unroll
  for (int ct = 0; ct < 8; ++ct) acc[ct] = (f32x4){0.f, 0.f, 0.f, 0.f};
  float dacc = 0.f;

  for (int jt = 0; jt < ntiles; ++jt) {
    const int j0 = jt * 256;

    // ---- stage hT[0:128][jc0+j0 : +256] -> Bt, linear dest + swizzled source ----
#pragma unroll
    for (int s = 0; s < 8; ++s) {
      int L = s * 512 + t;          // 16B-granule index
      int row = L >> 5;             // ct row 0..127
      int boff = (L & 31) * 16;     // byte offset in 512B row
      const char* src = hTb + ((size_t)row * N + jc0 + j0) * 2 + (boff ^ ((row & 7) << 4));
      GLOAD16(src, (char*)Bt + L * 16);
    }

    // ---- mask words for this tile (one int4 = kq 0..3), L2-resident ----
    int4 mw = *reinterpret_cast<const int4*>(maskp + (j0 >> 5));

    __syncthreads();  // drains vmcnt: Bt staged

#pragma unroll
    for (int kq = 0; kq < 4; ++kq) {
      // B-fragments from LDS (swizzled read)
      short8 bf[8];
      const int byte0 = hf * 256 + kq * 64 + kb * 16;
#pragma unroll
      for (int ct = 0; ct < 8; ++ct) {
        int row = ct * 16 + arow;
        int off = row * 512 + (byte0 ^ ((row & 7) << 4));
        bf[ct] = *reinterpret_cast<const short8*>((const char*)Bt + off);
      }
      // attention weights -> A-fragment; bits kb*8..+8 of word kq
      const unsigned w8 =
          (((unsigned)(kq == 0 ? mw.x : kq == 1 ? mw.y : kq == 2 ? mw.z : mw.w)) >>
           (kb * 8)) & 0xffu;
      float4 sv0 = *reinterpret_cast<const float4*>(s2p + j0 + kq * 32);
      float4 sv1 = *reinterpret_cast<const float4*>(s2p + j0 + kq * 32 + 4);
      const float* sf0 = reinterpret_cast<const float*>(&sv0);
      const float* sf1 = reinterpret_cast<const float*>(&sv1);
      short8 af;
#pragma unroll
      for (int e = 0; e < 4; ++e) {
        float pre = s1v + sf0[e];
        float lr = fmaxf(pre, ALPHA * pre);
        float w = __builtin_amdgcn_exp2f(fmaf(lr, L2E, -mvl));
        w = ((w8 >> e) & 1u) ? w : 0.f;
        dacc += w;
        af[e] = (short)f2bf(w);
      }
#pragma unroll
      for (int e = 0; e < 4; ++e) {
        float pre = s1v + sf1[e];
        float lr = fmaxf(pre, ALPHA * pre);
        float w = __builtin_amdgcn_exp2f(fmaf(lr, L2E, -mvl));
        w = ((w8 >> (4 + e)) & 1u) ? w : 0.f;
        dacc += w;
        af[4 + e] = (short)f2bf(w);
      }
#pragma unroll
      for (int ct = 0; ct < 8; ++ct)
        acc[ct] = __builtin_amdgcn_mfma_f32_16x16x32_bf16(af, bf[ct], acc[ct], 0, 0, 0);
    }

    __syncthreads();  // all waves done reading Bt before next stage
  }

  // ---- denominator partials: lanes {r, r+16, r+32, r+48} share row r ----
  dacc += __shfl_xor(dacc, 16);
  dacc += __shfl_xor(dacc, 32);
  if (lane < 16) Dred[wid][lane] = dacc;

  // ---- combine the two hf-halves' k-partials in LDS (reuse Bt) ----
  float (*Hred)[132] = (float(*)[132])(void*)Bt;  // 64 x 132 x 4B
  // C/D layout (m89-verified): col = ct*16 + arow, row-in-group = kb*4 + r
  if (hf == 0) {
#pragma unroll
    for (int ct = 0; ct < 8; ++ct)
#pragma unroll
      for (int r = 0; r < 4; ++r)
        Hred[g * 16 + kb * 4 + r][ct * 16 + arow] = acc[ct][r];
  }
  __syncthreads();
  if (hf == 1) {
#pragma unroll
    for (int ct = 0; ct < 8; ++ct)
#pragma unroll
      for (int r = 0; r < 4; ++r)
        Hred[g * 16 + kb * 4 + r][ct * 16 + arow] += acc[ct][r];
  }
  __syncthreads();

  if (t < 64)
    denp[(size_t)chunk * N + i0 + t] = Dred[t >> 4][t & 15] + Dred[(t >> 4) + 4][t & 15];

  for (int idx = t; idx < 64 * 128; idx += 512) {
    int r = idx >> 7, c = idx & 127;
    slab[((size_t)chunk * N + i0 + r) * 128 + c] = Hred[r][c];
  }
}

// ---------------- Kernel 3: combine chunks, divide, ELU ---------------------------
__global__ __launch_bounds__(256) void k_fin(const float* __restrict__ slab,
                                             const float* __restrict__ denp,
                                             float* __restrict__ out, int nchunks) {
  const int idx = blockIdx.x * 256 + threadIdx.x;  // < N*FOUT
  const int i = idx >> 7;
  float den = 0.f, v = 0.f;
  for (int k = 0; k < nchunks; ++k) {
    den += denp[(size_t)k * N + i];
    v += slab[(size_t)k * N * FOUT + idx];
  }
  v /= den;
  out[idx] = v > 0.f ? v : (__expf(v) - 1.f);
}

extern "C" void kernel_launch(void* const* d_in, const int* in_sizes, int n_in,
                              void* d_out, int out_size, void* d_ws, size_t ws_size,
                              hipStream_t stream) {
  const float* inp = (const float*)d_in[0];   // [N][FIN] fp32
  const int* adj   = (const int*)d_in[1];     // [N][N] int32
  const float* Wm  = (const float*)d_in[2];   // [FIN][FOUT] fp32
  const float* av  = (const float*)d_in[3];   // [2*FOUT] fp32
  float* out = (float*)d_out;

  // workspace carve-up
  char* ws = (char*)d_ws;
  ushort_t* hT = (ushort_t*)ws;                               // 2 MB
  float* s1    = (float*)(ws + (size_t)FOUT * N * 2);         // 32 KB
  float* s2    = s1 + N;                                      // 32 KB
  float* s2mx  = s2 + N;                                      // 16 B (padded)
  unsigned char* mask = (unsigned char*)(s2mx + 4);           // 8 MB bitmask
  float* slab  = (float*)(mask + (size_t)N * N / 8);

  const size_t base = (size_t)FOUT * N * 2 + (size_t)N * 4 * 2 + 16 + (size_t)N * N / 8;
  int nchunks = 4;
  while (nchunks > 1) {
    size_t need = base + (size_t)nchunks * N * FOUT * 4 + (size_t)nchunks * N * 4;
    if (need <= ws_size) break;
    nchunks >>= 1;
  }
  float* denp = slab + (size_t)nchunks * N * FOUT;
  const int jc = N / nchunks;
  const int ntiles = jc / 256;

  k_pack<<<2048, 256, 0, stream>>>(adj, mask);
  k_h<<<N / 16, 256, 0, stream>>>(inp, Wm, av, hT, s1, s2);
  k_smax<<<1, 256, 0, stream>>>(s2, s2mx);
  k_attn<<<128 * nchunks, 512, 0, stream>>>((const unsigned int*)mask, hT, s1, s2,
                                            s2mx, slab, denp, jc, ntiles);
  k_fin<<<(N * FOUT) / 256, 256, 0, stream>>>(slab, denp, out, nchunks);
}